// Round 4
// baseline (463.578 us; speedup 1.0000x reference)
//
#include <hip/hip_runtime.h>
#include <stdint.h>

// Problem constants (fixed by the reference):
#define NB 4
#define NN 50000
#define NE 800000
#define NF 128

#define SCHUNK 49        // ceil(NN/1024): nodes per thread in the 1-block scan
#define LDW 136          // W-LDS / epilogue-tile row stride in bf16 (128 + 8 pad)

typedef __attribute__((ext_vector_type(8))) short  bfrag;    // 8 bf16 (4 VGPR)
typedef __attribute__((ext_vector_type(4))) float  ffrag;    // 4 fp32 acc
typedef __attribute__((ext_vector_type(4))) short  short4v;  // 8 B LDS store
typedef __attribute__((ext_vector_type(4))) unsigned int u32x4;

// fp32 -> bf16 round-to-nearest-even
__device__ inline unsigned short f2bf(float f) {
    unsigned int u = __builtin_bit_cast(unsigned int, f);
    u += 0x7fffu + ((u >> 16) & 1u);
    return (unsigned short)(u >> 16);
}
__device__ inline float bflo(unsigned int u) { return __builtin_bit_cast(float, u << 16); }
__device__ inline float bfhi(unsigned int u) { return __builtin_bit_cast(float, u & 0xffff0000u); }

// ---------------------------------------------------------------------------
// GEMM (+fused edge histogram): h[n][b][o] = bf16(sum_f x[m][f]*W[o][f])
// W staged to LDS once per block behind a single barrier; x streamed straight
// from global into MFMA fragments (no barriers in the K-loop).
// ---------------------------------------------------------------------------
__global__ __launch_bounds__(256) void gemm_kernel(
    const float* __restrict__ x,        // [M][NF] fp32
    const float* __restrict__ W,        // [NF][NF] fp32 (row = out feature)
    unsigned short* __restrict__ h,     // [NN][NB][NF] bf16, node-major
    const int* __restrict__ erow,       // fused histogram input
    int* __restrict__ cnt,              // fused histogram output (pre-zeroed)
    int M)
{
    __shared__ short wsh[128 * LDW];    // 34.8 KB: W bf16, then epilogue tile

    const int tid = threadIdx.x;

    // --- fused histogram (overlaps with W staging + first x loads) ---
    for (int e = blockIdx.x * 256 + tid; e < NE; e += gridDim.x * 256)
        atomicAdd(&cnt[erow[e]], 1);

    // --- stage W -> LDS bf16, once ---
#pragma unroll
    for (int it = 0; it < 16; ++it) {
        int idx = it * 256 + tid;       // float4 slot 0..4095
        int r   = idx >> 5;             // 0..127
        int c4  = idx & 31;
        float4 wv = *(const float4*)(W + (size_t)r * NF + c4 * 4);
        short4v wsv;
        wsv[0] = (short)f2bf(wv.x); wsv[1] = (short)f2bf(wv.y);
        wsv[2] = (short)f2bf(wv.z); wsv[3] = (short)f2bf(wv.w);
        *(short4v*)&wsh[r * LDW + c4 * 4] = wsv;
    }
    __syncthreads();

    const int w    = tid >> 6;
    const int lane = tid & 63;
    const int q    = lane >> 4;     // 0..3
    const int l15  = lane & 15;
    const int r0   = blockIdx.x * 128 + w * 32;

    // Clamped per-fragment x row pointers (clamp is safe: MFMA rows are
    // independent and out-of-range rows are never stored).
    const float* xp[2];
#pragma unroll
    for (int i = 0; i < 2; ++i) {
        int gr = r0 + i * 16 + l15;
        gr = gr < M ? gr : M - 1;
        xp[i] = x + (size_t)gr * NF + q * 8;
    }

    ffrag acc[2][8];
#pragma unroll
    for (int i = 0; i < 2; ++i)
#pragma unroll
        for (int j = 0; j < 8; ++j) acc[i][j] = (ffrag)0.f;

#pragma unroll 2
    for (int kc = 0; kc < 4; ++kc) {    // K-chunks of 32; NO barriers inside
        bfrag a[2];
#pragma unroll
        for (int i = 0; i < 2; ++i) {
            float4 u0 = *(const float4*)(xp[i] + kc * 32);
            float4 u1 = *(const float4*)(xp[i] + kc * 32 + 4);
            bfrag t;
            t[0] = (short)f2bf(u0.x); t[1] = (short)f2bf(u0.y);
            t[2] = (short)f2bf(u0.z); t[3] = (short)f2bf(u0.w);
            t[4] = (short)f2bf(u1.x); t[5] = (short)f2bf(u1.y);
            t[6] = (short)f2bf(u1.z); t[7] = (short)f2bf(u1.w);
            a[i] = t;
        }
#pragma unroll
        for (int j = 0; j < 8; ++j) {
            bfrag b = *(const bfrag*)&wsh[(j * 16 + l15) * LDW + kc * 32 + q * 8];
            acc[0][j] = __builtin_amdgcn_mfma_f32_16x16x32_bf16(
                a[0], b, acc[0][j], 0, 0, 0);
            acc[1][j] = __builtin_amdgcn_mfma_f32_16x16x32_bf16(
                a[1], b, acc[1][j], 0, 0, 0);
        }
    }

    // --- epilogue: repack through LDS (reuses wsh), coalesced 16 B stores ---
    __syncthreads();                    // all waves done reading W
    short* tile = wsh;                  // [128][LDW] bf16
#pragma unroll
    for (int i = 0; i < 2; ++i)
#pragma unroll
        for (int reg = 0; reg < 4; ++reg) {
            int row = w * 32 + i * 16 + q * 4 + reg;
#pragma unroll
            for (int j = 0; j < 8; ++j)
                tile[row * LDW + j * 16 + l15] = (short)f2bf(acc[i][j][reg]);
        }
    __syncthreads();
#pragma unroll
    for (int it = 0; it < 8; ++it) {
        int row = it * 16 + (tid >> 4);
        int m   = blockIdx.x * 128 + row;
        if (m < M) {
            int n  = m % NN;
            int bb = m / NN;
            uint4 v = *(const uint4*)&tile[row * LDW + (tid & 15) * 8];
            *(uint4*)(h + ((size_t)n * NB + bb) * NF + (tid & 15) * 8) = v;
        }
    }
}

// ---------------------------------------------------------------------------
// Single-block full exclusive scan: cnt[NN] -> rs[0..NN] (rs[NN] = NE).
// 1024 threads, SCHUNK=49 nodes/thread, two passes over L2-resident cnt.
// Replaces the old scan1+scan2 pair and removes the bsum indirection from
// scatter and spmm.
// ---------------------------------------------------------------------------
__global__ __launch_bounds__(1024) void scan_kernel(
    const int* __restrict__ cnt, int* __restrict__ rs)
{
    __shared__ int woffs[16];
    const int tid  = threadIdx.x;
    const int lane = tid & 63;
    const int wid  = tid >> 6;
    const int i0   = tid * SCHUNK;

    int sum = 0;
    for (int j = 0; j < SCHUNK; ++j) {
        int i = i0 + j;
        sum += (i < NN) ? cnt[i] : 0;
    }
    int incl = sum;
#pragma unroll
    for (int off = 1; off < 64; off <<= 1) {
        int t = __shfl_up(incl, off, 64);
        if (lane >= off) incl += t;
    }
    if (lane == 63) woffs[wid] = incl;
    __syncthreads();
    int woff = 0;
    for (int ww = 0; ww < wid; ++ww) woff += woffs[ww];
    int run = woff + incl - sum;        // exclusive offset of this chunk

    for (int j = 0; j < SCHUNK; ++j) {
        int i = i0 + j;
        if (i < NN) { rs[i] = run; run += cnt[i]; }
    }
    if (tid == 0) rs[NN] = NE;
}

// ---------------------------------------------------------------------------
// Scatter: slot within row via atomicSub on cnt (counts down to 0) -- the
// separate cursor array and its memset are gone.
// ---------------------------------------------------------------------------
__global__ void scatter_kernel(const int* __restrict__ row,
                               const int* __restrict__ col,
                               const float* __restrict__ val,
                               const int* __restrict__ rs,
                               int* __restrict__ cnt,
                               uint2* __restrict__ cv_s)
{
    int e = blockIdx.x * 256 + threadIdx.x;
    if (e < NE) {
        int r   = row[e];
        int p   = atomicSub(&cnt[r], 1) - 1;   // unique slot 0..count-1
        int dst = rs[r] + p;
        uint2 cv;
        cv.x = (unsigned)col[e];
        cv.y = __builtin_bit_cast(unsigned, val[e]);
        cv_s[dst] = cv;                        // single 8 B write per edge
    }
}

// ---------------------------------------------------------------------------
// SpMM: wave per output row; coalesced cv preload + readlane broadcast.
// This round: 8 gathers in flight per wave (was 4) -- latency-vs-BW probe.
// Gathers stay NORMAL loads: h has ~50% L2 hit rate worth preserving (nt
// would mark lines evict-first and inflate fill traffic).
// ---------------------------------------------------------------------------
__global__ __launch_bounds__(256) void spmm_kernel(
    const unsigned short* __restrict__ h,   // [NN][NB][NF] bf16
    const int* __restrict__ rs,             // full CSR offsets (rs[NN]=NE)
    const uint2* __restrict__ cv_s,         // packed (col, val)
    float* __restrict__ out)                // [NB][NN][NF] fp32
{
    const int w    = threadIdx.x >> 6;
    const int lane = threadIdx.x & 63;
    int r = blockIdx.x * 4 + w;
    if (r >= NN) return;
    r = __builtin_amdgcn_readfirstlane(r);  // wave-uniform by construction

    const int s = rs[r];
    const int e = rs[r + 1];
    const int b    = lane >> 4;
    const int loff = b * NF + (lane & 15) * 8;   // element offset within h row

    float acc[8];
#pragma unroll
    for (int k = 0; k < 8; ++k) acc[k] = 0.f;

    for (int base = s; base < e; base += 64) {
        const int n = min(64, e - base);
        // coalesced preload of up to 64 edges; inactive lanes -> (col=0,val=0)
        unsigned long long cvp = 0ull;
        if (lane < n)
            cvp = __builtin_nontemporal_load(
                      (const unsigned long long*)(cv_s + base + lane));
        const int cvx = (int)(unsigned)(cvp & 0xffffffffull);   // col
        const int cvy = (int)(unsigned)(cvp >> 32);             // val bits

        const int n8 = (n + 7) & ~7;   // padded: lanes >= n contribute 0
        for (int i = 0; i < n8; i += 8) {
            unsigned c[8];
            u32x4 q[8];
#pragma unroll
            for (int k = 0; k < 8; ++k)
                c[k] = (unsigned)__builtin_amdgcn_readlane(cvx, i + k);
#pragma unroll
            for (int k = 0; k < 8; ++k)
                q[k] = *(const u32x4*)(h + (size_t)c[k] * (NB * NF) + loff);
#pragma unroll
            for (int k = 0; k < 8; ++k) {
                const float v = __builtin_bit_cast(
                    float, __builtin_amdgcn_readlane(cvy, i + k));
                acc[0] += v * bflo(q[k][0]); acc[1] += v * bfhi(q[k][0]);
                acc[2] += v * bflo(q[k][1]); acc[3] += v * bfhi(q[k][1]);
                acc[4] += v * bflo(q[k][2]); acc[5] += v * bfhi(q[k][2]);
                acc[6] += v * bflo(q[k][3]); acc[7] += v * bfhi(q[k][3]);
            }
        }
    }

    float* op = out + ((size_t)b * NN + r) * NF + (lane & 15) * 8;
    *(float4*)op       = make_float4(acc[0], acc[1], acc[2], acc[3]);
    *(float4*)(op + 4) = make_float4(acc[4], acc[5], acc[6], acc[7]);
}

// ---------------------------------------------------------------------------
extern "C" void kernel_launch(void* const* d_in, const int* in_sizes, int n_in,
                              void* d_out, int out_size, void* d_ws, size_t ws_size,
                              hipStream_t stream)
{
    const float* x    = (const float*)d_in[0];
    const float* W    = (const float*)d_in[1];
    const int*   erow = (const int*)d_in[2];
    const int*   ecol = (const int*)d_in[3];
    const float* ev   = (const float*)d_in[4];
    float*       out  = (float*)d_out;

    char*  ws  = (char*)d_ws;
    size_t off = 0;
    auto alloc = [&](size_t bytes) -> void* {
        void* p = ws + off;
        off += (bytes + 255) & ~(size_t)255;
        return p;
    };
    unsigned short* h = (unsigned short*)alloc((size_t)NN * NB * NF * sizeof(unsigned short)); // 51.2 MB
    int*   rs   = (int*)  alloc((size_t)(NN + 1) * sizeof(int));
    int*   cnt  = (int*)  alloc((size_t)NN * sizeof(int));
    uint2* cv_s = (uint2*)alloc((size_t)NE * sizeof(uint2));

    hipMemsetAsync(cnt, 0, (size_t)NN * sizeof(int), stream);

    const int M = NB * NN;
    gemm_kernel<<<(M + 127) / 128, 256, 0, stream>>>(x, W, h, erow, cnt, M);

    scan_kernel<<<1, 1024, 0, stream>>>(cnt, rs);
    scatter_kernel<<<(NE + 255) / 256, 256, 0, stream>>>(erow, ecol, ev, rs,
                                                         cnt, cv_s);

    spmm_kernel<<<(NN + 3) / 4, 256, 0, stream>>>(h, rs, cv_s, out);
}